// Round 6
// baseline (161.931 us; speedup 1.0000x reference)
//
#include <hip/hip_runtime.h>
#include <stdint.h>

typedef short v8s __attribute__((ext_vector_type(8)));
typedef float v4f __attribute__((ext_vector_type(4)));

#define TPB 768

// ---- LDS layout (bytes) ----
// scatter : X0 bf16 [32x][28y][32c] rows 64B swz(row&3)<<4   @0        57,344
// conv0   : X0 -> X1 bf16 [32x][26y][32c] rows 64B           @106,496  53,248 (ends 159,744)
// conv1   : X1 -> X2 bf16 [32x][26y][64c] rows 128B swz&7    @0       106,496 (X0 dead)
// conv2   : X2 -> X3 bf16 [768p][32c] rows 64B swz&3         @106,496  49,152 (X1 dead)
// MLP     : Ya f32 @0 (16,384), Yb f32 @16,384 (16,384)               (X2 dead)
#define X0_OFF 0
#define X1_OFF 106496
#define X2_OFF 0
#define X3_OFF 106496
#define YA_OFF 0
#define YB_OFF 16384
#define SMEM_BYTES 159744

// ws fragment bases (16B units): conv0 50 frags, conv1 36, conv2 72 (x64 lanes)
#define WS0_U 0
#define WS1_U 3200
#define WS2_U 5504
#define WS_UNITS 10112

__device__ __forceinline__ uint16_t f2b(float f) {
    uint32_t u = __float_as_uint(f);
    return (uint16_t)((u + 0x7FFFu + ((u >> 16) & 1u)) >> 16);
}
__device__ __forceinline__ float b2f(uint16_t h) {
    return __uint_as_float(((uint32_t)h) << 16);
}

// ---------------- weight prep: pack A-fragments (bf16) into d_ws ----------------
// fid = (t*KF + kf)*MT_TOT + m ; lane l holds W[m*16+(l&15)][kf*32+(l>>4)*8 + j]
__global__ void prep_weights(const float* __restrict__ w0,
                             const float* __restrict__ w1,
                             const float* __restrict__ w2,
                             uint8_t* __restrict__ ws)
{
    int u = blockIdx.x * 256 + threadIdx.x;
    if (u >= WS_UNITS) return;
    int l = u & 63, fid = u >> 6;
    const float* src; int IC, KS_, t, kf, m;
    if (fid < 50)      { src = w0; IC = 26; KS_ = 5; t = fid >> 1; kf = 0; m = fid & 1; }
    else if (fid < 86) { int v = fid - 50; src = w1; IC = 32; KS_ = 3; t = v >> 2; kf = 0; m = v & 3; }
    else               { int v = fid - 86; src = w2; IC = 64; KS_ = 3; t = v >> 3; kf = (v >> 2) & 1; m = v & 3; }
    int oc = m * 16 + (l & 15);
    int kb = kf * 32 + ((l >> 4) * 8);
    int ky = t / KS_, kx = t - ky * KS_;
    v8s out;
#pragma unroll
    for (int j = 0; j < 8; ++j) {
        int k = kb + j;
        float v = (k < IC) ? src[((oc * IC + k) * KS_ + ky) * KS_ + kx] : 0.f;
        out[j] = (short)f2b(v);
    }
    ((v8s*)ws)[u] = out;
}

// ---------------- conv core: tap-decomposed implicit GEMM on MFMA ----------------
// 12 waves x 4 N-tiles each = 48 tiles of 16 pixels
template<int MT, int KF, int TAPS, int KS, int PAD,
         int IN_OFF, int IN_SH, int IN_ROWS, int WS_BASE, int MT_TOT>
__device__ __forceinline__ void conv_core(const uint8_t* smem, const v8s* __restrict__ wsv,
                                          int l, const int* px, const int* py,
                                          v4f (&acc)[MT][4])
{
    const int kgoff = ((l >> 4) << 4);
    constexpr int MSK = (IN_SH == 7) ? 7 : 3;
    for (int t = 0; t < TAPS; ++t) {
        const int ky = t / KS, kx = t - ky * KS;
        const int dx = ky - PAD, dy = kx - PAD;
        v8s af[MT][KF];
#pragma unroll
        for (int m = 0; m < MT; ++m)
#pragma unroll
            for (int kf = 0; kf < KF; ++kf)
                af[m][kf] = wsv[WS_BASE + ((t * KF + kf) * MT_TOT + m) * 64 + l];
#pragma unroll
        for (int i = 0; i < 4; ++i) {
            const int xi = px[i] + dx;
            const int rowp = xi * IN_ROWS + py[i] + dy + PAD;   // y via physical pad
            int a = ((rowp << IN_SH) | kgoff) ^ ((rowp & MSK) << 4);
            a = ((unsigned)xi < 32u) ? a : kgoff;               // x OOB -> zeroed row 0
            a += IN_OFF;
            const v8s bf0 = *(const v8s*)(smem + a);
#pragma unroll
            for (int m = 0; m < MT; ++m)
                acc[m][i] = __builtin_amdgcn_mfma_f32_16x16x32_bf16(af[m][0], bf0, acc[m][i], 0, 0, 0);
            if (KF == 2) {
                const v8s bf1 = *(const v8s*)(smem + (a ^ 64));
#pragma unroll
                for (int m = 0; m < MT; ++m)
                    acc[m][i] = __builtin_amdgcn_mfma_f32_16x16x32_bf16(af[m][1], bf1, acc[m][i], 0, 0, 0);
            }
        }
    }
}

// ---------------- conv epilogue: bias+relu+bf16 pack, packed b64 stores ----------------
template<int MTOT, int M0, int M1, int OUT_OFF, int OUT_SH, int OUT_ROWS, int OUT_PAD>
__device__ __forceinline__ void conv_epi(uint8_t* smem, const float* __restrict__ bias,
                                         v4f (&acc)[MTOT][4], const int* px, const int* py, int kg)
{
    constexpr int MSK = (OUT_SH == 7) ? 7 : 3;
#pragma unroll
    for (int m = M0; m < M1; ++m) {
        const float* bp = bias + m * 16 + kg * 4;
        const float bb0 = bp[0], bb1 = bp[1], bb2 = bp[2], bb3 = bp[3];
#pragma unroll
        for (int i = 0; i < 4; ++i) {
            const float v0 = fmaxf(acc[m][i][0] + bb0, 0.f);
            const float v1 = fmaxf(acc[m][i][1] + bb1, 0.f);
            const float v2 = fmaxf(acc[m][i][2] + bb2, 0.f);
            const float v3 = fmaxf(acc[m][i][3] + bb3, 0.f);
            uint2 pk;
            pk.x = (uint32_t)f2b(v0) | ((uint32_t)f2b(v1) << 16);
            pk.y = (uint32_t)f2b(v2) | ((uint32_t)f2b(v3) << 16);
            const int rowp = px[i] * OUT_ROWS + py[i] + OUT_PAD;
            const int coff = (m - M0) * 32 + (kg << 3);
            const int a = OUT_OFF + (((rowp << OUT_SH) | coff) ^ ((rowp & MSK) << 4));
            *(uint2*)(smem + a) = pk;
        }
    }
}

// ---------------- gather one conv2 half into registers (threads < 512) ----------------
__device__ __forceinline__ void gather_half(const uint8_t* smem,
                                            const float* __restrict__ rooms,
                                            const int* __restrict__ rp,
                                            int gr, int gg, int h, float* yreg)
{
    if ((gg >> 2) != h) return;
    const int gl = gg & 3;
    const int pxr = rp[gr * 2], pyr = rp[gr * 2 + 1];
    const float* rr = rooms + gr * 324;
    float s0=0,s1=0,s2=0,s3=0,s4=0,s5=0,s6=0,s7=0;
#pragma unroll
    for (int ci = 0; ci < 6; ++ci)
#pragma unroll
        for (int cj = 0; cj < 6; ++cj) {
            const float mv = rr[ci * 6 + cj];
            if (mv != 0.f) {
                const int p = (pxr + ci) * 24 + pyr + cj;
                const int a = X3_OFF + (((p << 6) | (gl << 4)) ^ ((p & 3) << 4));
                const v8s v = *(const v8s*)(smem + a);
                s0 = fmaf(b2f((uint16_t)v[0]), mv, s0);
                s1 = fmaf(b2f((uint16_t)v[1]), mv, s1);
                s2 = fmaf(b2f((uint16_t)v[2]), mv, s2);
                s3 = fmaf(b2f((uint16_t)v[3]), mv, s3);
                s4 = fmaf(b2f((uint16_t)v[4]), mv, s4);
                s5 = fmaf(b2f((uint16_t)v[5]), mv, s5);
                s6 = fmaf(b2f((uint16_t)v[6]), mv, s6);
                s7 = fmaf(b2f((uint16_t)v[7]), mv, s7);
            }
        }
    yreg[0]=s0; yreg[1]=s1; yreg[2]=s2; yreg[3]=s3;
    yreg[4]=s4; yreg[5]=s5; yreg[6]=s6; yreg[7]=s7;
}

// ---------------- MLP layer (f32), 512 active threads x 8 outputs, chunked loads ----------------
template<bool RELU, bool TOGLOBAL>
__device__ __forceinline__ void mlp_layer(uint8_t* smem, int inoff, int outoff,
                                          const float* __restrict__ W,
                                          const float* __restrict__ bias,
                                          float* __restrict__ outg, int tid)
{
    if (tid >= 512) return;
    const int og = tid >> 6, r = tid & 63;
    const int ogs = __builtin_amdgcn_readfirstlane(og);
    const int swz = (r & 7) << 4;
    float acc[8];
#pragma unroll
    for (int oo = 0; oo < 8; ++oo) acc[oo] = bias[ogs * 8 + oo];
    const float* Wb = W + ogs * 8 * 64;
#pragma unroll
    for (int cg = 0; cg < 16; ++cg) {
        const v4f v = *(const v4f*)(smem + inoff + ((r * 256 + cg * 16) ^ swz));
#pragma unroll
        for (int oo = 0; oo < 8; ++oo) {
            const float* wr = Wb + oo * 64 + cg * 4;
            acc[oo] = fmaf(wr[0], v[0], acc[oo]);
            acc[oo] = fmaf(wr[1], v[1], acc[oo]);
            acc[oo] = fmaf(wr[2], v[2], acc[oo]);
            acc[oo] = fmaf(wr[3], v[3], acc[oo]);
        }
    }
    if (RELU)
#pragma unroll
        for (int oo = 0; oo < 8; ++oo) acc[oo] = fmaxf(acc[oo], 0.f);
    const v4f o0 = {acc[0], acc[1], acc[2], acc[3]};
    const v4f o1 = {acc[4], acc[5], acc[6], acc[7]};
    if (TOGLOBAL) {
        *(v4f*)(outg + r * 64 + ogs * 8)     = o0;
        *(v4f*)(outg + r * 64 + ogs * 8 + 4) = o1;
    } else {
        *(v4f*)(smem + outoff + ((r * 256 + ogs * 32) ^ swz))      = o0;
        *(v4f*)(smem + outoff + ((r * 256 + ogs * 32 + 16) ^ swz)) = o1;
    }
}

// ---------------- fused main kernel: one block (12 waves) per sample ----------------
// 768 threads = 12 waves = 3 waves/SIMD with the LDS-pinned 1 block/CU ->
// 512/3 = ~170 total regs/thread available: conv2's full working set fits, no spill.
__global__ __attribute__((amdgpu_flat_work_group_size(TPB, TPB), amdgpu_waves_per_eu(3, 3)))
void fused_main(const int* __restrict__ rpos,
                const float* __restrict__ rooms,
                const float* __restrict__ emb,
                const float* __restrict__ b0, const float* __restrict__ b1,
                const float* __restrict__ b2,
                const float* __restrict__ rw0, const float* __restrict__ rb0,
                const float* __restrict__ rw1, const float* __restrict__ rb1,
                const float* __restrict__ rw2, const float* __restrict__ rb2,
                const uint8_t* __restrict__ ws,
                float* __restrict__ out)
{
    __shared__ __align__(16) uint8_t smem[SMEM_BYTES];
    const int tid = threadIdx.x, n = blockIdx.x;
    const int* rp = rpos + n * 128;
    const v8s* wsv = (const v8s*)ws;

    // ---- P1: register scatter -> bf16 X0 (1 thread = 1 pixel) + pad-row zero ----
    if (tid < 512) {
        // zero X0 y-pad rows: 128 rows x 4 slots = 512 units
        const int rowi = tid >> 2, slot = tid & 3;
        const int x = rowi >> 2, yp = rowi & 3;
        const int row = x * 28 + ((yp < 2) ? yp : yp + 24);
        *(v8s*)(smem + X0_OFF + (((row << 6) | (slot << 4)) ^ ((row & 3) << 4))) =
            (v8s){0,0,0,0,0,0,0,0};
    }
    {
        const int x = (tid * 2731) >> 16;       // tid / 24
        const int y = tid - x * 24;
        float a[26];
#pragma unroll
        for (int c = 0; c < 26; ++c) a[c] = 0.f;
        a[9] = 1.f;                              // background channel
        for (int r = 0; r < 64; ++r) {
            const int ci = x - rp[2 * r], cj = y - rp[2 * r + 1];
            if ((unsigned)ci < 6u && (unsigned)cj < 6u) {
                const int cell = ci * 6 + cj;
                const float* rr = rooms + r * 324;
                const float m = rr[cell];
                if (m != 0.f) {
#pragma unroll
                    for (int c = 0; c < 9; ++c) a[c] += rr[c * 36 + cell];
                    const float* er = emb + r * 16;
#pragma unroll
                    for (int e = 0; e < 16; ++e) a[10 + e] = fmaf(er[e], m, a[10 + e]);
                }
            }
        }
        const int row = x * 28 + y + 2;
        const int swz = (row & 3) << 4;
#pragma unroll
        for (int cg = 0; cg < 4; ++cg) {
            v8s o;
#pragma unroll
            for (int j = 0; j < 8; ++j) {
                const int c = cg * 8 + j;
                o[j] = (short)((c < 26) ? f2b(a[c]) : (uint16_t)0);
            }
            *(v8s*)(smem + X0_OFF + (((row << 6) | (cg << 4)) ^ swz)) = o;
        }
    }
    __syncthreads();

    // per-thread MFMA geometry: wave wv owns N-tiles wv*4 .. wv*4+3
    const int l = tid & 63, wv = tid >> 6, kg = l >> 4;
    int px[4], py[4];
#pragma unroll
    for (int i = 0; i < 4; ++i) {
        const int p = (wv * 4 + i) * 16 + (l & 15);
        const int x = (p * 2731) >> 16;
        px[i] = x; py[i] = p - x * 24;
    }

    // ---- P2: conv0 (26->32, 5x5) + X1 pad zero ----
    {
        if (tid < 256) {
            const int rowi = tid >> 2, slot = tid & 3;
            const int x = rowi >> 1;
            const int rowp = x * 26 + ((rowi & 1) ? 25 : 0);
            *(v8s*)(smem + X1_OFF + (((rowp << 6) | (slot << 4)) ^ ((rowp & 3) << 4))) =
                (v8s){0,0,0,0,0,0,0,0};
        }
        v4f acc[2][4];
#pragma unroll
        for (int m = 0; m < 2; ++m)
#pragma unroll
            for (int i = 0; i < 4; ++i) acc[m][i] = (v4f){0.f,0.f,0.f,0.f};
        conv_core<2,1,25,5,2, X0_OFF,6,28, WS0_U,2>(smem, wsv, l, px, py, acc);
        conv_epi<2,0,2, X1_OFF,6,26,1>(smem, b0, acc, px, py, kg);
    }
    __syncthreads();

    // ---- P3: conv1 (32->64, 3x3) + X2 pad zero ----
    {
        if (tid < 512) {
            const int rowi = tid >> 3, slot = tid & 7;
            const int x = rowi >> 1;
            const int rowp = x * 26 + ((rowi & 1) ? 25 : 0);
            *(v8s*)(smem + X2_OFF + (((rowp << 7) | (slot << 4)) ^ ((rowp & 7) << 4))) =
                (v8s){0,0,0,0,0,0,0,0};
        }
        v4f acc[4][4];
#pragma unroll
        for (int m = 0; m < 4; ++m)
#pragma unroll
            for (int i = 0; i < 4; ++i) acc[m][i] = (v4f){0.f,0.f,0.f,0.f};
        conv_core<4,1,9,3,1, X1_OFF,6,26, WS1_U,4>(smem, wsv, l, px, py, acc);
        conv_epi<4,0,4, X2_OFF,7,26,1>(smem, b1, acc, px, py, kg);
    }
    __syncthreads();

    // ---- P4: conv2 (64->64, 3x3) single K-sweep, two-stage epilogue + gather ----
    float yreg[8];
    {
        v4f acc[4][4];
#pragma unroll
        for (int m = 0; m < 4; ++m)
#pragma unroll
            for (int i = 0; i < 4; ++i) acc[m][i] = (v4f){0.f,0.f,0.f,0.f};
        conv_core<4,2,9,3,1, X2_OFF,7,26, WS2_U,4>(smem, wsv, l, px, py, acc);
        // half 0 (oc 0..31): X3 write does not touch X2, no barrier needed first
        conv_epi<4,0,2, X3_OFF,6,24,0>(smem, b2, acc, px, py, kg);
        __syncthreads();
        if (tid < 512) gather_half(smem, rooms, rp, tid >> 3, tid & 7, 0, yreg);
        __syncthreads();
        // half 1 (oc 32..63)
        conv_epi<4,2,4, X3_OFF,6,24,0>(smem, b2, acc, px, py, kg);
        __syncthreads();
        if (tid < 512) gather_half(smem, rooms, rp, tid >> 3, tid & 7, 1, yreg);
        __syncthreads();
    }

    // ---- P5: assemble Y f32 [r][c] (swizzled rows); thread (gr,gg) holds Y[gr][gg*8..+8]
    if (tid < 512) {
        const int gr = tid >> 3, gg = tid & 7;
        const int base = gr * 256 + gg * 32;
        const int swz = (gr & 7) << 4;
        *(v4f*)(smem + YA_OFF + (base ^ swz))        = (v4f){yreg[0], yreg[1], yreg[2], yreg[3]};
        *(v4f*)(smem + YA_OFF + ((base + 16) ^ swz)) = (v4f){yreg[4], yreg[5], yreg[6], yreg[7]};
    }
    __syncthreads();

    // ---- P6: 3-layer room MLP (f32) ----
    mlp_layer<true,  false>(smem, YA_OFF, YB_OFF, rw0, rb0, nullptr, tid);
    __syncthreads();
    mlp_layer<true,  false>(smem, YB_OFF, YA_OFF, rw1, rb1, nullptr, tid);
    __syncthreads();
    mlp_layer<false, true >(smem, YA_OFF, 0, rw2, rb2, out + n * 4096, tid);
}

extern "C" void kernel_launch(void* const* d_in, const int* in_sizes, int n_in,
                              void* d_out, int out_size, void* d_ws, size_t ws_size,
                              hipStream_t stream) {
    const int*   rpos  = (const int*)  d_in[0];
    const float* rooms = (const float*)d_in[1];
    const float* emb   = (const float*)d_in[2];
    const float* w0    = (const float*)d_in[3];
    const float* b0    = (const float*)d_in[4];
    const float* w1    = (const float*)d_in[5];
    const float* b1    = (const float*)d_in[6];
    const float* w2    = (const float*)d_in[7];
    const float* b2    = (const float*)d_in[8];
    const float* rw0   = (const float*)d_in[9];
    const float* rb0   = (const float*)d_in[10];
    const float* rw1   = (const float*)d_in[11];
    const float* rb1   = (const float*)d_in[12];
    const float* rw2   = (const float*)d_in[13];
    const float* rb2   = (const float*)d_in[14];
    float* out = (float*)d_out;
    uint8_t* ws = (uint8_t*)d_ws;

    const int n = in_sizes[0] / 128;   // samples (512)
    hipLaunchKernelGGL(prep_weights, dim3((WS_UNITS + 255) / 256), dim3(256), 0, stream,
                       w0, w1, w2, ws);
    hipLaunchKernelGGL(fused_main, dim3(n), dim3(TPB), 0, stream,
                       rpos, rooms, emb, b0, b1, b2,
                       rw0, rb0, rw1, rb1, rw2, rb2, ws, out);
}

// Round 7
// 152.996 us; speedup vs baseline: 1.0584x; 1.0584x over previous
//
#include <hip/hip_runtime.h>
#include <stdint.h>

typedef short v8s __attribute__((ext_vector_type(8)));
typedef float v4f __attribute__((ext_vector_type(4)));

#define TPB 1024

// ---- LDS layout (bytes) ----
// scatter : X0 bf16 [32x][28y][32c] rows 64B swz(row&3)<<4   @0        57,344
// conv0   : X0 -> X1 bf16 [32x][26y][32c] rows 64B           @106,496  53,248 (ends 159,744)
// conv1   : X1 -> X2 bf16 [32x][26y][64c] rows 128B swz&7    @0       106,496 (X0 dead)
// conv2   : X2 -> X3 bf16 [768p][32c] rows 64B swz&3         @106,496  49,152 (X1 dead)
// MLP     : Ya f32 @0 (16,384), Yb f32 @16,384 (16,384)               (X2 dead)
#define X0_OFF 0
#define X1_OFF 106496
#define X2_OFF 0
#define X3_OFF 106496
#define YA_OFF 0
#define YB_OFF 16384
#define SMEM_BYTES 159744

// ws fragment bases (16B units): conv0 50 frags, conv1 36, conv2 72 (x64 lanes)
#define WS0_U 0
#define WS1_U 3200
#define WS2_U 5504
#define WS_UNITS 10112

__device__ __forceinline__ uint16_t f2b(float f) {
    uint32_t u = __float_as_uint(f);
    return (uint16_t)((u + 0x7FFFu + ((u >> 16) & 1u)) >> 16);
}
__device__ __forceinline__ float b2f(uint16_t h) {
    return __uint_as_float(((uint32_t)h) << 16);
}

// ---------------- weight prep: pack A-fragments (bf16) into d_ws ----------------
// fid = (t*KF + kf)*MT_TOT + m ; lane l holds W[m*16+(l&15)][kf*32+(l>>4)*8 + j]
__global__ void prep_weights(const float* __restrict__ w0,
                             const float* __restrict__ w1,
                             const float* __restrict__ w2,
                             uint8_t* __restrict__ ws)
{
    int u = blockIdx.x * 256 + threadIdx.x;
    if (u >= WS_UNITS) return;
    int l = u & 63, fid = u >> 6;
    const float* src; int IC, KS_, t, kf, m;
    if (fid < 50)      { src = w0; IC = 26; KS_ = 5; t = fid >> 1; kf = 0; m = fid & 1; }
    else if (fid < 86) { int v = fid - 50; src = w1; IC = 32; KS_ = 3; t = v >> 2; kf = 0; m = v & 3; }
    else               { int v = fid - 86; src = w2; IC = 64; KS_ = 3; t = v >> 3; kf = (v >> 2) & 1; m = v & 3; }
    int oc = m * 16 + (l & 15);
    int kb = kf * 32 + ((l >> 4) * 8);
    int ky = t / KS_, kx = t - ky * KS_;
    v8s out;
#pragma unroll
    for (int j = 0; j < 8; ++j) {
        int k = kb + j;
        float v = (k < IC) ? src[((oc * IC + k) * KS_ + ky) * KS_ + kx] : 0.f;
        out[j] = (short)f2b(v);
    }
    ((v8s*)ws)[u] = out;
}

// ---------------- conv core: tap-decomposed implicit GEMM on MFMA ----------------
// 16 waves x 3 N-tiles each = 48 tiles of 16 pixels
template<int MT, int KF, int TAPS, int KS, int PAD,
         int IN_OFF, int IN_SH, int IN_ROWS, int WS_BASE, int MBASE, int MT_TOT>
__device__ __forceinline__ void conv_core(const uint8_t* smem, const v8s* __restrict__ wsv,
                                          int l, const int* px, const int* py,
                                          v4f (&acc)[MT][3])
{
    const int kgoff = ((l >> 4) << 4);
    constexpr int MSK = (IN_SH == 7) ? 7 : 3;
    for (int t = 0; t < TAPS; ++t) {
        const int ky = t / KS, kx = t - ky * KS;
        const int dx = ky - PAD, dy = kx - PAD;
        v8s af[MT][KF];
#pragma unroll
        for (int m = 0; m < MT; ++m)
#pragma unroll
            for (int kf = 0; kf < KF; ++kf)
                af[m][kf] = wsv[WS_BASE + ((t * KF + kf) * MT_TOT + MBASE + m) * 64 + l];
#pragma unroll
        for (int i = 0; i < 3; ++i) {
            const int xi = px[i] + dx;
            const int rowp = xi * IN_ROWS + py[i] + dy + PAD;   // y via physical pad
            int a = ((rowp << IN_SH) | kgoff) ^ ((rowp & MSK) << 4);
            a = ((unsigned)xi < 32u) ? a : kgoff;               // x OOB -> zeroed row 0
            a += IN_OFF;
            const v8s bf0 = *(const v8s*)(smem + a);
#pragma unroll
            for (int m = 0; m < MT; ++m)
                acc[m][i] = __builtin_amdgcn_mfma_f32_16x16x32_bf16(af[m][0], bf0, acc[m][i], 0, 0, 0);
            if (KF == 2) {
                const v8s bf1 = *(const v8s*)(smem + (a ^ 64));
#pragma unroll
                for (int m = 0; m < MT; ++m)
                    acc[m][i] = __builtin_amdgcn_mfma_f32_16x16x32_bf16(af[m][1], bf1, acc[m][i], 0, 0, 0);
            }
        }
    }
}

// ---------------- conv epilogue: bias+relu+bf16 pack, packed b64 stores ----------------
// MB = global oc-block base (bias indexing); local m spans acc.
template<int MT, int MB, int OUT_OFF, int OUT_SH, int OUT_ROWS, int OUT_PAD>
__device__ __forceinline__ void conv_epi(uint8_t* smem, const float* __restrict__ bias,
                                         v4f (&acc)[MT][3], const int* px, const int* py, int kg)
{
    constexpr int MSK = (OUT_SH == 7) ? 7 : 3;
#pragma unroll
    for (int m = 0; m < MT; ++m) {
        const float* bp = bias + (MB + m) * 16 + kg * 4;
        const float bb0 = bp[0], bb1 = bp[1], bb2 = bp[2], bb3 = bp[3];
#pragma unroll
        for (int i = 0; i < 3; ++i) {
            const float v0 = fmaxf(acc[m][i][0] + bb0, 0.f);
            const float v1 = fmaxf(acc[m][i][1] + bb1, 0.f);
            const float v2 = fmaxf(acc[m][i][2] + bb2, 0.f);
            const float v3 = fmaxf(acc[m][i][3] + bb3, 0.f);
            uint2 pk;
            pk.x = (uint32_t)f2b(v0) | ((uint32_t)f2b(v1) << 16);
            pk.y = (uint32_t)f2b(v2) | ((uint32_t)f2b(v3) << 16);
            const int rowp = px[i] * OUT_ROWS + py[i] + OUT_PAD;
            const int coff = m * 32 + (kg << 3);
            const int a = OUT_OFF + (((rowp << OUT_SH) | coff) ^ ((rowp & MSK) << 4));
            *(uint2*)(smem + a) = pk;
        }
    }
}

// ---------------- gather one conv2 half into registers (threads < 512) ----------------
__device__ __forceinline__ void gather_half(const uint8_t* smem,
                                            const float* __restrict__ rooms,
                                            const int* __restrict__ rp,
                                            int gr, int gg, int h, float* yreg)
{
    if ((gg >> 2) != h) return;
    const int gl = gg & 3;
    const int pxr = rp[gr * 2], pyr = rp[gr * 2 + 1];
    const float* rr = rooms + gr * 324;
    float s0=0,s1=0,s2=0,s3=0,s4=0,s5=0,s6=0,s7=0;
#pragma unroll
    for (int ci = 0; ci < 6; ++ci)
#pragma unroll
        for (int cj = 0; cj < 6; ++cj) {
            const float mv = rr[ci * 6 + cj];
            if (mv != 0.f) {
                const int p = (pxr + ci) * 24 + pyr + cj;
                const int a = X3_OFF + (((p << 6) | (gl << 4)) ^ ((p & 3) << 4));
                const v8s v = *(const v8s*)(smem + a);
                s0 = fmaf(b2f((uint16_t)v[0]), mv, s0);
                s1 = fmaf(b2f((uint16_t)v[1]), mv, s1);
                s2 = fmaf(b2f((uint16_t)v[2]), mv, s2);
                s3 = fmaf(b2f((uint16_t)v[3]), mv, s3);
                s4 = fmaf(b2f((uint16_t)v[4]), mv, s4);
                s5 = fmaf(b2f((uint16_t)v[5]), mv, s5);
                s6 = fmaf(b2f((uint16_t)v[6]), mv, s6);
                s7 = fmaf(b2f((uint16_t)v[7]), mv, s7);
            }
        }
    yreg[0]=s0; yreg[1]=s1; yreg[2]=s2; yreg[3]=s3;
    yreg[4]=s4; yreg[5]=s5; yreg[6]=s6; yreg[7]=s7;
}

// ---------------- MLP layer (f32), 1024 threads: 16 groups x 4 outputs, chunked loads ----------------
template<bool RELU, bool TOGLOBAL>
__device__ __forceinline__ void mlp_layer(uint8_t* smem, int inoff, int outoff,
                                          const float* __restrict__ W,
                                          const float* __restrict__ bias,
                                          float* __restrict__ outg, int tid)
{
    const int og = tid >> 6, r = tid & 63;
    const int ogs = __builtin_amdgcn_readfirstlane(og);
    const int swz = (r & 7) << 4;
    float acc[4];
#pragma unroll
    for (int oo = 0; oo < 4; ++oo) acc[oo] = bias[ogs * 4 + oo];
    const float* Wb = W + ogs * 4 * 64;
#pragma unroll
    for (int cg = 0; cg < 16; ++cg) {
        const v4f v = *(const v4f*)(smem + inoff + ((r * 256 + cg * 16) ^ swz));
#pragma unroll
        for (int oo = 0; oo < 4; ++oo) {
            const float* wr = Wb + oo * 64 + cg * 4;
            acc[oo] = fmaf(wr[0], v[0], acc[oo]);
            acc[oo] = fmaf(wr[1], v[1], acc[oo]);
            acc[oo] = fmaf(wr[2], v[2], acc[oo]);
            acc[oo] = fmaf(wr[3], v[3], acc[oo]);
        }
    }
    if (RELU)
#pragma unroll
        for (int oo = 0; oo < 4; ++oo) acc[oo] = fmaxf(acc[oo], 0.f);
    const v4f o0 = {acc[0], acc[1], acc[2], acc[3]};
    if (TOGLOBAL) *(v4f*)(outg + r * 64 + ogs * 4) = o0;
    else          *(v4f*)(smem + outoff + ((r * 256 + ogs * 16) ^ swz)) = o0;
}

// ---------------- fused main kernel: one block (16 waves) per sample ----------------
// Every phase is designed to fit a 64-arch/64-accum register split at 4 waves/EU:
// conv2 runs as two MT=2 sweeps; MLP accumulates in chunks (no yrow[64]).
__global__ __launch_bounds__(TPB)
void fused_main(const int* __restrict__ rpos,
                const float* __restrict__ rooms,
                const float* __restrict__ emb,
                const float* __restrict__ b0, const float* __restrict__ b1,
                const float* __restrict__ b2,
                const float* __restrict__ rw0, const float* __restrict__ rb0,
                const float* __restrict__ rw1, const float* __restrict__ rb1,
                const float* __restrict__ rw2, const float* __restrict__ rb2,
                const uint8_t* __restrict__ ws,
                float* __restrict__ out)
{
    __shared__ __align__(16) uint8_t smem[SMEM_BYTES];
    const int tid = threadIdx.x, n = blockIdx.x;
    const int* rp = rpos + n * 128;
    const v8s* wsv = (const v8s*)ws;

    // ---- P1: register scatter -> bf16 X0 (no atomics, no f32 buffer) ----
    if (tid < 768) {
        const int x = (tid * 2731) >> 16;       // tid / 24
        const int y = tid - x * 24;
        float a[26];
#pragma unroll
        for (int c = 0; c < 26; ++c) a[c] = 0.f;
        a[9] = 1.f;                              // background channel
        for (int r = 0; r < 64; ++r) {
            const int ci = x - rp[2 * r], cj = y - rp[2 * r + 1];
            if ((unsigned)ci < 6u && (unsigned)cj < 6u) {
                const int cell = ci * 6 + cj;
                const float* rr = rooms + r * 324;
                const float m = rr[cell];
                if (m != 0.f) {
#pragma unroll
                    for (int c = 0; c < 9; ++c) a[c] += rr[c * 36 + cell];
                    const float* er = emb + r * 16;
#pragma unroll
                    for (int e = 0; e < 16; ++e) a[10 + e] = fmaf(er[e], m, a[10 + e]);
                }
            }
        }
        const int row = x * 28 + y + 2;
        const int swz = (row & 3) << 4;
#pragma unroll
        for (int cg = 0; cg < 4; ++cg) {
            v8s o;
#pragma unroll
            for (int j = 0; j < 8; ++j) {
                const int c = cg * 8 + j;
                o[j] = (short)((c < 26) ? f2b(a[c]) : (uint16_t)0);
            }
            *(v8s*)(smem + X0_OFF + (((row << 6) | (cg << 4)) ^ swz)) = o;
        }
    } else {
        // zero X0 y-pad rows: 128 rows x 4 slots, 256 threads x 2
        const int base = (tid - 768) * 2;
#pragma unroll
        for (int k = 0; k < 2; ++k) {
            const int u = base + k;
            const int rowi = u >> 2, slot = u & 3;
            const int x = rowi >> 2, yp = rowi & 3;
            const int row = x * 28 + ((yp < 2) ? yp : yp + 24);
            *(v8s*)(smem + X0_OFF + (((row << 6) | (slot << 4)) ^ ((row & 3) << 4))) =
                (v8s){0,0,0,0,0,0,0,0};
        }
    }
    __syncthreads();

    // per-thread MFMA geometry
    const int l = tid & 63, wv = tid >> 6, kg = l >> 4;
    int px[3], py[3];
#pragma unroll
    for (int i = 0; i < 3; ++i) {
        const int p = (wv + 16 * i) * 16 + (l & 15);
        const int x = (p * 2731) >> 16;
        px[i] = x; py[i] = p - x * 24;
    }

    // ---- P2: conv0 (26->32, 5x5) + X1 pad zero ----
    {
        if (tid < 256) {
            const int rowi = tid >> 2, slot = tid & 3;
            const int x = rowi >> 1;
            const int rowp = x * 26 + ((rowi & 1) ? 25 : 0);
            *(v8s*)(smem + X1_OFF + (((rowp << 6) | (slot << 4)) ^ ((rowp & 3) << 4))) =
                (v8s){0,0,0,0,0,0,0,0};
        }
        v4f acc[2][3];
#pragma unroll
        for (int m = 0; m < 2; ++m)
#pragma unroll
            for (int i = 0; i < 3; ++i) acc[m][i] = (v4f){0.f,0.f,0.f,0.f};
        conv_core<2,1,25,5,2, X0_OFF,6,28, WS0_U,0,2>(smem, wsv, l, px, py, acc);
        conv_epi<2,0, X1_OFF,6,26,1>(smem, b0, acc, px, py, kg);
    }
    __syncthreads();

    // ---- P3: conv1 (32->64, 3x3) + X2 pad zero ----
    {
        if (tid < 512) {
            const int rowi = tid >> 3, slot = tid & 7;
            const int x = rowi >> 1;
            const int rowp = x * 26 + ((rowi & 1) ? 25 : 0);
            *(v8s*)(smem + X2_OFF + (((rowp << 7) | (slot << 4)) ^ ((rowp & 7) << 4))) =
                (v8s){0,0,0,0,0,0,0,0};
        }
        v4f acc[4][3];
#pragma unroll
        for (int m = 0; m < 4; ++m)
#pragma unroll
            for (int i = 0; i < 3; ++i) acc[m][i] = (v4f){0.f,0.f,0.f,0.f};
        conv_core<4,1,9,3,1, X1_OFF,6,26, WS1_U,0,4>(smem, wsv, l, px, py, acc);
        conv_epi<4,0, X2_OFF,7,26,1>(smem, b1, acc, px, py, kg);
    }
    __syncthreads();

    // ---- P4: conv2 (64->64, 3x3) as TWO MT=2 sweeps, each fused with gather ----
    float yreg[8];
    {
        v4f acc[2][3];
#pragma unroll
        for (int m = 0; m < 2; ++m)
#pragma unroll
            for (int i = 0; i < 3; ++i) acc[m][i] = (v4f){0.f,0.f,0.f,0.f};
        conv_core<2,2,9,3,1, X2_OFF,7,26, WS2_U,0,4>(smem, wsv, l, px, py, acc);
        conv_epi<2,0, X3_OFF,6,24,0>(smem, b2, acc, px, py, kg);   // X3 disjoint from X2
    }
    __syncthreads();
    if (tid < 512) gather_half(smem, rooms, rp, tid >> 3, tid & 7, 0, yreg);
    __syncthreads();
    {
        v4f acc[2][3];
#pragma unroll
        for (int m = 0; m < 2; ++m)
#pragma unroll
            for (int i = 0; i < 3; ++i) acc[m][i] = (v4f){0.f,0.f,0.f,0.f};
        conv_core<2,2,9,3,1, X2_OFF,7,26, WS2_U,2,4>(smem, wsv, l, px, py, acc);
        conv_epi<2,2, X3_OFF,6,24,0>(smem, b2, acc, px, py, kg);
    }
    __syncthreads();
    if (tid < 512) gather_half(smem, rooms, rp, tid >> 3, tid & 7, 1, yreg);
    __syncthreads();

    // ---- P5: assemble Y f32 [r][c] (swizzled rows); thread (gr,gg) holds Y[gr][gg*8..+8]
    if (tid < 512) {
        const int gr = tid >> 3, gg = tid & 7;
        const int base = gr * 256 + gg * 32;
        const int swz = (gr & 7) << 4;
        *(v4f*)(smem + YA_OFF + (base ^ swz))        = (v4f){yreg[0], yreg[1], yreg[2], yreg[3]};
        *(v4f*)(smem + YA_OFF + ((base + 16) ^ swz)) = (v4f){yreg[4], yreg[5], yreg[6], yreg[7]};
    }
    __syncthreads();

    // ---- P6: 3-layer room MLP (f32) ----
    mlp_layer<true,  false>(smem, YA_OFF, YB_OFF, rw0, rb0, nullptr, tid);
    __syncthreads();
    mlp_layer<true,  false>(smem, YB_OFF, YA_OFF, rw1, rb1, nullptr, tid);
    __syncthreads();
    mlp_layer<false, true >(smem, YA_OFF, 0, rw2, rb2, out + n * 4096, tid);
}

extern "C" void kernel_launch(void* const* d_in, const int* in_sizes, int n_in,
                              void* d_out, int out_size, void* d_ws, size_t ws_size,
                              hipStream_t stream) {
    const int*   rpos  = (const int*)  d_in[0];
    const float* rooms = (const float*)d_in[1];
    const float* emb   = (const float*)d_in[2];
    const float* w0    = (const float*)d_in[3];
    const float* b0    = (const float*)d_in[4];
    const float* w1    = (const float*)d_in[5];
    const float* b1    = (const float*)d_in[6];
    const float* w2    = (const float*)d_in[7];
    const float* b2    = (const float*)d_in[8];
    const float* rw0   = (const float*)d_in[9];
    const float* rb0   = (const float*)d_in[10];
    const float* rw1   = (const float*)d_in[11];
    const float* rb1   = (const float*)d_in[12];
    const float* rw2   = (const float*)d_in[13];
    const float* rb2   = (const float*)d_in[14];
    float* out = (float*)d_out;
    uint8_t* ws = (uint8_t*)d_ws;

    const int n = in_sizes[0] / 128;   // samples (512)
    hipLaunchKernelGGL(prep_weights, dim3((WS_UNITS + 255) / 256), dim3(256), 0, stream,
                       w0, w1, w2, ws);
    hipLaunchKernelGGL(fused_main, dim3(n), dim3(TPB), 0, stream,
                       rpos, rooms, emb, b0, b1, b2,
                       rw0, rb0, rw1, rb1, rw2, rb2, ws, out);
}

// Round 8
// 133.225 us; speedup vs baseline: 1.2155x; 1.1484x over previous
//
#include <hip/hip_runtime.h>
#include <hip/hip_bf16.h>
#include <stdint.h>

typedef short v8s __attribute__((ext_vector_type(8)));
typedef float v4f __attribute__((ext_vector_type(4)));

#define TPB 1024

// ---- LDS layout (bytes) ----
// scatter : X0 bf16 [32x][28y][32c] rows 64B swz(row&3)<<4   @0        57,344
// conv0   : X0 -> X1 bf16 [32x][26y][32c] rows 64B           @106,496  53,248 (ends 159,744)
// conv1   : X1 -> X2 bf16 [32x][26y][64c] rows 128B swz&7    @0       106,496 (X0 dead)
// conv2   : X2 -> X3 bf16 [768p][32c] rows 64B swz&3         @106,496  49,152 (X1 dead)
// MLP     : Ya f32 @0 (16,384), Yb f32 @16,384 (16,384)               (X2 dead)
#define X0_OFF 0
#define X1_OFF 106496
#define X2_OFF 0
#define X3_OFF 106496
#define YA_OFF 0
#define YB_OFF 16384
#define SMEM_BYTES 159744

// ws fragment bases (16B units): conv0 50 frags, conv1 36, conv2 72 (x64 lanes)
#define WS0_U 0
#define WS1_U 3200
#define WS2_U 5504
#define WS_UNITS 10112

__device__ __forceinline__ uint16_t f2b(float f) {
    __hip_bfloat16 h = __float2bfloat16(f);          // hw v_cvt (RNE), pairs fuse to cvt_pk
    return *reinterpret_cast<uint16_t*>(&h);
}
__device__ __forceinline__ uint32_t pkbf(float lo, float hi) {
    return (uint32_t)f2b(lo) | ((uint32_t)f2b(hi) << 16);
}
__device__ __forceinline__ float b2f(uint16_t h) {
    return __uint_as_float(((uint32_t)h) << 16);
}

// ---------------- weight prep: pack A-fragments (bf16) into d_ws ----------------
// fid = (t*KF + kf)*MT_TOT + m ; lane l holds W[m*16+(l&15)][kf*32+(l>>4)*8 + j]
__global__ void prep_weights(const float* __restrict__ w0,
                             const float* __restrict__ w1,
                             const float* __restrict__ w2,
                             uint8_t* __restrict__ ws)
{
    int u = blockIdx.x * 256 + threadIdx.x;
    if (u >= WS_UNITS) return;
    int l = u & 63, fid = u >> 6;
    const float* src; int IC, KS_, t, kf, m;
    if (fid < 50)      { src = w0; IC = 26; KS_ = 5; t = fid >> 1; kf = 0; m = fid & 1; }
    else if (fid < 86) { int v = fid - 50; src = w1; IC = 32; KS_ = 3; t = v >> 2; kf = 0; m = v & 3; }
    else               { int v = fid - 86; src = w2; IC = 64; KS_ = 3; t = v >> 3; kf = (v >> 2) & 1; m = v & 3; }
    int oc = m * 16 + (l & 15);
    int kb = kf * 32 + ((l >> 4) * 8);
    int ky = t / KS_, kx = t - ky * KS_;
    v8s out;
#pragma unroll
    for (int j = 0; j < 8; ++j) {
        int k = kb + j;
        float v = (k < IC) ? src[((oc * IC + k) * KS_ + ky) * KS_ + kx] : 0.f;
        out[j] = (short)f2b(v);
    }
    ((v8s*)ws)[u] = out;
}

// ---------------- conv core: tap-decomposed implicit GEMM on MFMA ----------------
// 16 waves x 3 N-tiles each = 48 tiles of 16 pixels
template<int MT, int KF, int TAPS, int KS, int PAD,
         int IN_OFF, int IN_SH, int IN_ROWS, int WS_BASE, int MT_TOT>
__device__ __forceinline__ void conv_core(const uint8_t* smem, const v8s* __restrict__ wsv,
                                          int l, const int* px, const int* py,
                                          v4f (&acc)[MT][3])
{
    const int kgoff = ((l >> 4) << 4);
    constexpr int MSK = (IN_SH == 7) ? 7 : 3;
    for (int t = 0; t < TAPS; ++t) {
        const int ky = t / KS, kx = t - ky * KS;
        const int dx = ky - PAD, dy = kx - PAD;
        v8s af[MT][KF];
#pragma unroll
        for (int m = 0; m < MT; ++m)
#pragma unroll
            for (int kf = 0; kf < KF; ++kf)
                af[m][kf] = wsv[WS_BASE + ((t * KF + kf) * MT_TOT + m) * 64 + l];
#pragma unroll
        for (int i = 0; i < 3; ++i) {
            const int xi = px[i] + dx;
            const int rowp = xi * IN_ROWS + py[i] + dy + PAD;   // y via physical pad
            int a = ((rowp << IN_SH) | kgoff) ^ ((rowp & MSK) << 4);
            a = ((unsigned)xi < 32u) ? a : kgoff;               // x OOB -> zeroed row 0
            a += IN_OFF;
            const v8s bf0 = *(const v8s*)(smem + a);
#pragma unroll
            for (int m = 0; m < MT; ++m)
                acc[m][i] = __builtin_amdgcn_mfma_f32_16x16x32_bf16(af[m][0], bf0, acc[m][i], 0, 0, 0);
            if (KF == 2) {
                const v8s bf1 = *(const v8s*)(smem + (a ^ 64));
#pragma unroll
                for (int m = 0; m < MT; ++m)
                    acc[m][i] = __builtin_amdgcn_mfma_f32_16x16x32_bf16(af[m][1], bf1, acc[m][i], 0, 0, 0);
            }
        }
    }
}

// ---------------- conv epilogue: bias+relu+bf16 pack, packed b64 stores ----------------
template<int MTOT, int M0, int M1, int OUT_OFF, int OUT_SH, int OUT_ROWS, int OUT_PAD>
__device__ __forceinline__ void conv_epi(uint8_t* smem, const float* __restrict__ bias,
                                         v4f (&acc)[MTOT][3], const int* px, const int* py, int kg)
{
    constexpr int MSK = (OUT_SH == 7) ? 7 : 3;
#pragma unroll
    for (int m = M0; m < M1; ++m) {
        const float* bp = bias + m * 16 + kg * 4;
        const float bb0 = bp[0], bb1 = bp[1], bb2 = bp[2], bb3 = bp[3];
#pragma unroll
        for (int i = 0; i < 3; ++i) {
            const float v0 = fmaxf(acc[m][i][0] + bb0, 0.f);
            const float v1 = fmaxf(acc[m][i][1] + bb1, 0.f);
            const float v2 = fmaxf(acc[m][i][2] + bb2, 0.f);
            const float v3 = fmaxf(acc[m][i][3] + bb3, 0.f);
            uint2 pk;
            pk.x = pkbf(v0, v1);
            pk.y = pkbf(v2, v3);
            const int rowp = px[i] * OUT_ROWS + py[i] + OUT_PAD;
            const int coff = (m - M0) * 32 + (kg << 3);
            const int a = OUT_OFF + (((rowp << OUT_SH) | coff) ^ ((rowp & MSK) << 4));
            *(uint2*)(smem + a) = pk;
        }
    }
}

// ---------------- gather one conv2 half: 256 all-active threads (4 per room) ----------------
__device__ __forceinline__ void gather_half(const uint8_t* smem,
                                            const float* __restrict__ rooms,
                                            const int* __restrict__ rp,
                                            int gr, int gl, float* yreg)
{
    const int pxr = rp[gr * 2], pyr = rp[gr * 2 + 1];
    const float* rr = rooms + gr * 324;
    float s0=0,s1=0,s2=0,s3=0,s4=0,s5=0,s6=0,s7=0;
#pragma unroll
    for (int ci = 0; ci < 6; ++ci)
#pragma unroll
        for (int cj = 0; cj < 6; ++cj) {
            const float mv = rr[ci * 6 + cj];
            if (mv != 0.f) {
                const int p = (pxr + ci) * 24 + pyr + cj;
                const int a = X3_OFF + (((p << 6) | (gl << 4)) ^ ((p & 3) << 4));
                const v8s v = *(const v8s*)(smem + a);
                s0 = fmaf(b2f((uint16_t)v[0]), mv, s0);
                s1 = fmaf(b2f((uint16_t)v[1]), mv, s1);
                s2 = fmaf(b2f((uint16_t)v[2]), mv, s2);
                s3 = fmaf(b2f((uint16_t)v[3]), mv, s3);
                s4 = fmaf(b2f((uint16_t)v[4]), mv, s4);
                s5 = fmaf(b2f((uint16_t)v[5]), mv, s5);
                s6 = fmaf(b2f((uint16_t)v[6]), mv, s6);
                s7 = fmaf(b2f((uint16_t)v[7]), mv, s7);
            }
        }
    yreg[0]=s0; yreg[1]=s1; yreg[2]=s2; yreg[3]=s3;
    yreg[4]=s4; yreg[5]=s5; yreg[6]=s6; yreg[7]=s7;
}

// ---------------- MLP layer (f32), 1024 threads: 16 groups x 4 outputs, chunked loads ----------------
template<bool RELU>
__device__ __forceinline__ void mlp_layer(uint8_t* smem, int inoff, int outoff,
                                          const float* __restrict__ W,
                                          const float* __restrict__ bias, int tid)
{
    const int og = tid >> 6, r = tid & 63;
    const int ogs = __builtin_amdgcn_readfirstlane(og);
    const int swz = (r & 7) << 4;
    float acc[4];
#pragma unroll
    for (int oo = 0; oo < 4; ++oo) acc[oo] = bias[ogs * 4 + oo];
    const float* Wb = W + ogs * 4 * 64;
#pragma unroll
    for (int cg = 0; cg < 16; ++cg) {
        const v4f v = *(const v4f*)(smem + inoff + ((r * 256 + cg * 16) ^ swz));
#pragma unroll
        for (int oo = 0; oo < 4; ++oo) {
            const float* wr = Wb + oo * 64 + cg * 4;
            acc[oo] = fmaf(wr[0], v[0], acc[oo]);
            acc[oo] = fmaf(wr[1], v[1], acc[oo]);
            acc[oo] = fmaf(wr[2], v[2], acc[oo]);
            acc[oo] = fmaf(wr[3], v[3], acc[oo]);
        }
    }
    if (RELU)
#pragma unroll
        for (int oo = 0; oo < 4; ++oo) acc[oo] = fmaxf(acc[oo], 0.f);
    const v4f o0 = {acc[0], acc[1], acc[2], acc[3]};
    *(v4f*)(smem + outoff + ((r * 256 + ogs * 16) ^ swz)) = o0;
}

// ---------------- fused main kernel: one block (16 waves) per sample ----------------
__global__ __launch_bounds__(TPB)
void fused_main(const int* __restrict__ rpos,
                const float* __restrict__ rooms,
                const float* __restrict__ emb,
                const float* __restrict__ b0, const float* __restrict__ b1,
                const float* __restrict__ b2,
                const float* __restrict__ rw0, const float* __restrict__ rb0,
                const float* __restrict__ rw1, const float* __restrict__ rb1,
                const float* __restrict__ rw2, const float* __restrict__ rb2,
                const uint8_t* __restrict__ ws,
                float* __restrict__ out)
{
    __shared__ __align__(16) uint8_t smem[SMEM_BYTES];
    const int tid = threadIdx.x, n = blockIdx.x;
    const int* rp = rpos + n * 128;
    const v8s* wsv = (const v8s*)ws;

    // ---- P1: register scatter -> bf16 X0 (no atomics, no f32 buffer) ----
    if (tid < 768) {
        const int x = (tid * 2731) >> 16;       // tid / 24
        const int y = tid - x * 24;
        float a[26];
#pragma unroll
        for (int c = 0; c < 26; ++c) a[c] = 0.f;
        a[9] = 1.f;                              // background channel
        for (int r = 0; r < 64; ++r) {
            const int ci = x - rp[2 * r], cj = y - rp[2 * r + 1];
            if ((unsigned)ci < 6u && (unsigned)cj < 6u) {
                const int cell = ci * 6 + cj;
                const float* rr = rooms + r * 324;
                const float m = rr[cell];
                if (m != 0.f) {
#pragma unroll
                    for (int c = 0; c < 9; ++c) a[c] += rr[c * 36 + cell];
                    const float* er = emb + r * 16;
#pragma unroll
                    for (int e = 0; e < 16; ++e) a[10 + e] = fmaf(er[e], m, a[10 + e]);
                }
            }
        }
        const int row = x * 28 + y + 2;
        const int swz = (row & 3) << 4;
#pragma unroll
        for (int cg = 0; cg < 4; ++cg) {
            uint2 pk0, pk1;
            pk0.x = pkbf(a[cg*8+0] * ((cg*8+0) < 26 ? 1.f : 0.f), (cg*8+1) < 26 ? a[cg*8+1 < 26 ? cg*8+1 : 0] : 0.f);
            // (channels >= 26 are zero-padded; cg<4 -> indices up to 31)
            float c0 = (cg*8+0 < 26) ? a[(cg*8+0) < 26 ? cg*8+0 : 0] : 0.f;
            float c1 = (cg*8+1 < 26) ? a[(cg*8+1) < 26 ? cg*8+1 : 0] : 0.f;
            float c2 = (cg*8+2 < 26) ? a[(cg*8+2) < 26 ? cg*8+2 : 0] : 0.f;
            float c3 = (cg*8+3 < 26) ? a[(cg*8+3) < 26 ? cg*8+3 : 0] : 0.f;
            float c4 = (cg*8+4 < 26) ? a[(cg*8+4) < 26 ? cg*8+4 : 0] : 0.f;
            float c5 = (cg*8+5 < 26) ? a[(cg*8+5) < 26 ? cg*8+5 : 0] : 0.f;
            float c6 = (cg*8+6 < 26) ? a[(cg*8+6) < 26 ? cg*8+6 : 0] : 0.f;
            float c7 = (cg*8+7 < 26) ? a[(cg*8+7) < 26 ? cg*8+7 : 0] : 0.f;
            pk0.x = pkbf(c0, c1); pk0.y = pkbf(c2, c3);
            pk1.x = pkbf(c4, c5); pk1.y = pkbf(c6, c7);
            const int a0 = X0_OFF + (((row << 6) | (cg << 4)) ^ swz);
            *(uint2*)(smem + a0)     = pk0;
            *(uint2*)(smem + a0 + 8) = pk1;
        }
    } else {
        // zero X0 y-pad rows: 128 rows x 4 slots, 256 threads x 2
        const int base = (tid - 768) * 2;
#pragma unroll
        for (int k = 0; k < 2; ++k) {
            const int u = base + k;
            const int rowi = u >> 2, slot = u & 3;
            const int x = rowi >> 2, yp = rowi & 3;
            const int row = x * 28 + ((yp < 2) ? yp : yp + 24);
            *(v8s*)(smem + X0_OFF + (((row << 6) | (slot << 4)) ^ ((row & 3) << 4))) =
                (v8s){0,0,0,0,0,0,0,0};
        }
    }
    __syncthreads();

    // per-thread MFMA geometry
    const int l = tid & 63, wv = tid >> 6, kg = l >> 4;
    int px[3], py[3];
#pragma unroll
    for (int i = 0; i < 3; ++i) {
        const int p = (wv + 16 * i) * 16 + (l & 15);
        const int x = (p * 2731) >> 16;
        px[i] = x; py[i] = p - x * 24;
    }

    // ---- P2: conv0 (26->32, 5x5) + X1 pad zero ----
    {
        if (tid < 256) {
            const int rowi = tid >> 2, slot = tid & 3;
            const int x = rowi >> 1;
            const int rowp = x * 26 + ((rowi & 1) ? 25 : 0);
            *(v8s*)(smem + X1_OFF + (((rowp << 6) | (slot << 4)) ^ ((rowp & 3) << 4))) =
                (v8s){0,0,0,0,0,0,0,0};
        }
        v4f acc[2][3];
#pragma unroll
        for (int m = 0; m < 2; ++m)
#pragma unroll
            for (int i = 0; i < 3; ++i) acc[m][i] = (v4f){0.f,0.f,0.f,0.f};
        conv_core<2,1,25,5,2, X0_OFF,6,28, WS0_U,2>(smem, wsv, l, px, py, acc);
        conv_epi<2,0,2, X1_OFF,6,26,1>(smem, b0, acc, px, py, kg);
    }
    __syncthreads();

    // ---- P3: conv1 (32->64, 3x3) + X2 pad zero ----
    {
        if (tid < 512) {
            const int rowi = tid >> 3, slot = tid & 7;
            const int x = rowi >> 1;
            const int rowp = x * 26 + ((rowi & 1) ? 25 : 0);
            *(v8s*)(smem + X2_OFF + (((rowp << 7) | (slot << 4)) ^ ((rowp & 7) << 4))) =
                (v8s){0,0,0,0,0,0,0,0};
        }
        v4f acc[4][3];
#pragma unroll
        for (int m = 0; m < 4; ++m)
#pragma unroll
            for (int i = 0; i < 3; ++i) acc[m][i] = (v4f){0.f,0.f,0.f,0.f};
        conv_core<4,1,9,3,1, X1_OFF,6,26, WS1_U,4>(smem, wsv, l, px, py, acc);
        conv_epi<4,0,4, X2_OFF,7,26,1>(smem, b1, acc, px, py, kg);
    }
    __syncthreads();

    // ---- P4: conv2 (64->64, 3x3) single K-sweep, two-stage epilogue + gather ----
    float yregA[8], yregB[8];
    {
        v4f acc[4][3];
#pragma unroll
        for (int m = 0; m < 4; ++m)
#pragma unroll
            for (int i = 0; i < 3; ++i) acc[m][i] = (v4f){0.f,0.f,0.f,0.f};
        conv_core<4,2,9,3,1, X2_OFF,7,26, WS2_U,4>(smem, wsv, l, px, py, acc);
        // half 0 (oc 0..31): X3 write does not touch X2, no barrier needed first
        conv_epi<4,0,2, X3_OFF,6,24,0>(smem, b2, acc, px, py, kg);
        __syncthreads();
        if (tid < 256) gather_half(smem, rooms, rp, tid >> 2, tid & 3, yregA);
        __syncthreads();
        // half 1 (oc 32..63)
        conv_epi<4,2,4, X3_OFF,6,24,0>(smem, b2, acc, px, py, kg);
        __syncthreads();
        if (tid < 256) gather_half(smem, rooms, rp, tid >> 2, tid & 3, yregB);
        __syncthreads();
    }

    // ---- P5: assemble Y f32 [r][c] (swizzled rows); thread (gr,gl) holds 16 channels
    if (tid < 256) {
        const int gr = tid >> 2, gl = tid & 3;
        const int swz = (gr & 7) << 4;
        const int baseA = gr * 256 + gl * 32;            // oc = gl*8 .. +8 (half 0)
        const int baseB = baseA + 128;                   // oc = 32 + gl*8 .. +8 (half 1)
        *(v4f*)(smem + YA_OFF + (baseA ^ swz))        = (v4f){yregA[0], yregA[1], yregA[2], yregA[3]};
        *(v4f*)(smem + YA_OFF + ((baseA + 16) ^ swz)) = (v4f){yregA[4], yregA[5], yregA[6], yregA[7]};
        *(v4f*)(smem + YA_OFF + (baseB ^ swz))        = (v4f){yregB[0], yregB[1], yregB[2], yregB[3]};
        *(v4f*)(smem + YA_OFF + ((baseB + 16) ^ swz)) = (v4f){yregB[4], yregB[5], yregB[6], yregB[7]};
    }
    __syncthreads();

    // ---- P6: 3-layer room MLP (f32), all in LDS ----
    mlp_layer<true >(smem, YA_OFF, YB_OFF, rw0, rb0, tid);
    __syncthreads();
    mlp_layer<true >(smem, YB_OFF, YA_OFF, rw1, rb1, tid);
    __syncthreads();
    mlp_layer<false>(smem, YA_OFF, YB_OFF, rw2, rb2, tid);
    __syncthreads();

    // ---- P7: coalesced output store: out[n][r][oc], 1024 threads x v4f = 16KB ----
    {
        const int r = tid >> 4, cg = tid & 15;
        const int swz = (r & 7) << 4;
        const v4f v = *(const v4f*)(smem + YB_OFF + ((r * 256 + cg * 16) ^ swz));
        *(v4f*)(out + n * 4096 + r * 64 + cg * 4) = v;
    }
}

extern "C" void kernel_launch(void* const* d_in, const int* in_sizes, int n_in,
                              void* d_out, int out_size, void* d_ws, size_t ws_size,
                              hipStream_t stream) {
    const int*   rpos  = (const int*)  d_in[0];
    const float* rooms = (const float*)d_in[1];
    const float* emb   = (const float*)d_in[2];
    const float* w0    = (const float*)d_in[3];
    const float* b0    = (const float*)d_in[4];
    const float* w1    = (const float*)d_in[5];
    const float* b1    = (const float*)d_in[6];
    const float* w2    = (const float*)d_in[7];
    const float* b2    = (const float*)d_in[8];
    const float* rw0   = (const float*)d_in[9];
    const float* rb0   = (const float*)d_in[10];
    const float* rw1   = (const float*)d_in[11];
    const float* rb1   = (const float*)d_in[12];
    const float* rw2   = (const float*)d_in[13];
    const float* rb2   = (const float*)d_in[14];
    float* out = (float*)d_out;
    uint8_t* ws = (uint8_t*)d_ws;

    const int n = in_sizes[0] / 128;   // samples (512)
    hipLaunchKernelGGL(prep_weights, dim3((WS_UNITS + 255) / 256), dim3(256), 0, stream,
                       w0, w1, w2, ws);
    hipLaunchKernelGGL(fused_main, dim3(n), dim3(TPB), 0, stream,
                       rpos, rooms, emb, b0, b1, b2,
                       rw0, rb0, rw1, rb1, rw2, rb2, ws, out);
}